// Round 4
// baseline (280.350 us; speedup 1.0000x reference)
//
#include <hip/hip_runtime.h>
#include <hip/hip_bf16.h>

#define B_ 4
#define S_ 2048
#define E_ 1024
#define H_ 16
#define D_ 64
#define QSCALE 0.18033688011112042f  // (1/8) * log2(e) : softmax in exp2 domain

typedef __attribute__((ext_vector_type(8))) short bf16x8;  // 8 bf16 (4 VGPRs)
typedef __attribute__((ext_vector_type(4))) float f32x4;   // MFMA C/D frag

__device__ __forceinline__ f32x4 mfma16(bf16x8 a, bf16x8 b, f32x4 c) {
    return __builtin_amdgcn_mfma_f32_16x16x32_bf16(a, b, c, 0, 0, 0);
}
__device__ __forceinline__ short f2bs(float f) {
    __hip_bfloat16 h = __float2bfloat16(f);
    return *reinterpret_cast<short*>(&h);
}
// async global->LDS, 16 B per lane. LDS dst = wave-uniform base + lane*16.
__device__ __forceinline__ void glds16(const void* gptr, void* lptr) {
    __builtin_amdgcn_global_load_lds(
        (const __attribute__((address_space(1))) unsigned int*)(unsigned long long)gptr,
        (__attribute__((address_space(3))) unsigned int*)(unsigned int)(unsigned long long)lptr,
        16, 0, 0);
}
// superblock index: 128-B rows, 8 rows per 1040-B superblock (bank-balanced pad)
__device__ __forceinline__ int sbi(int r, int cshort) {
    return (r >> 3) * 520 + (r & 7) * 64 + cshort;
}

// ---------------------------------------------------------------------------
// Transpose-convert Wq/Wk/Wv (per head [1024][64] fp32) -> WT[48][64][1024] bf16
// ---------------------------------------------------------------------------
__global__ __launch_bounds__(256) void conv_wqkv(
    const float* __restrict__ Wq, const float* __restrict__ Wk,
    const float* __restrict__ Wv, short* __restrict__ WT)
{
    const int mat = blockIdx.x >> 4;
    const int kt  = blockIdx.x & 15;
    const int which = mat >> 4, h = mat & 15;
    const float* src = (which == 0 ? Wq : which == 1 ? Wk : Wv) + (size_t)h * E_ * D_;
    __shared__ float T[64][65];
    const int tid = threadIdx.x;
    const int k0 = kt * 64;
    #pragma unroll
    for (int it = 0; it < 4; ++it) {
        int lin = tid + it * 256;
        int kr = lin >> 4, dc = (lin & 15) * 4;
        const float4 v = *(const float4*)&src[(size_t)(k0 + kr) * D_ + dc];
        T[kr][dc] = v.x; T[kr][dc + 1] = v.y; T[kr][dc + 2] = v.z; T[kr][dc + 3] = v.w;
    }
    __syncthreads();
    #pragma unroll
    for (int it = 0; it < 4; ++it) {
        int lin = tid + it * 256;
        int dr = lin >> 4, kc = (lin & 15) * 4;
        ushort4 o;
        o.x = (unsigned short)f2bs(T[kc][dr]);
        o.y = (unsigned short)f2bs(T[kc + 1][dr]);
        o.z = (unsigned short)f2bs(T[kc + 2][dr]);
        o.w = (unsigned short)f2bs(T[kc + 3][dr]);
        *(ushort4*)&WT[((size_t)mat * 64 + dr) * E_ + k0 + kc] = o;
    }
}

// ---------------------------------------------------------------------------
// Transpose-convert Wp [1024][1024] fp32 -> WpT[n][k] bf16
// ---------------------------------------------------------------------------
__global__ __launch_bounds__(256) void conv_wp(
    const float* __restrict__ Wp, short* __restrict__ WpT)
{
    const int ktile = blockIdx.x & 15, ntile = blockIdx.x >> 4;
    const int k0 = ktile * 64, n0 = ntile * 64;
    __shared__ float T[64][65];
    const int tid = threadIdx.x;
    #pragma unroll
    for (int it = 0; it < 4; ++it) {
        int lin = tid + it * 256;
        int kr = lin >> 4, nc = (lin & 15) * 4;
        const float4 v = *(const float4*)&Wp[(size_t)(k0 + kr) * E_ + n0 + nc];
        T[kr][nc] = v.x; T[kr][nc + 1] = v.y; T[kr][nc + 2] = v.z; T[kr][nc + 3] = v.w;
    }
    __syncthreads();
    #pragma unroll
    for (int it = 0; it < 4; ++it) {
        int lin = tid + it * 256;
        int nr = lin >> 4, kc = (lin & 15) * 4;
        ushort4 o;
        o.x = (unsigned short)f2bs(T[kc][nr]);
        o.y = (unsigned short)f2bs(T[kc + 1][nr]);
        o.z = (unsigned short)f2bs(T[kc + 2][nr]);
        o.w = (unsigned short)f2bs(T[kc + 3][nr]);
        *(ushort4*)&WpT[(size_t)(n0 + nr) * E_ + k0 + kc] = o;
    }
}

// ---------------------------------------------------------------------------
// Fused QKV projection. Block: 256 rows x 1 head; 4 waves, each 64 rows x 192
// cols; BK=32; x staged wave-private (fp32->bf16); weights via dbuf glds.
// ---------------------------------------------------------------------------
__global__ __launch_bounds__(256, 2) void qkv_fused(
    const float* __restrict__ x, const short* __restrict__ WT,
    const float* __restrict__ bq, const float* __restrict__ bk,
    const float* __restrict__ bv,
    short* __restrict__ Qw, short* __restrict__ Kw, short* __restrict__ VTw)
{
    const int h = blockIdx.y;
    const int m0 = blockIdx.x * 256;
    __shared__ short Xs[4 * 64 * 72];      // 36.9 KB, wave-private 64x72 each
    __shared__ short Wt3[2][3 * 2080];     // dbuf: 3 mats x 4 sb x 520 (64-B rows, 16/sb)

    const int tid = threadIdx.x;
    const int lane = tid & 63, w = tid >> 6;
    const int l15 = lane & 15, qd = lane >> 4;

    f32x4 zero = {0.f, 0.f, 0.f, 0.f};
    f32x4 acc[3][4][4];
    #pragma unroll
    for (int a = 0; a < 3; ++a)
        #pragma unroll
        for (int b = 0; b < 4; ++b)
            #pragma unroll
            for (int c = 0; c < 4; ++c) acc[a][b][c] = zero;

    // prologue: weights k0=0 -> buf 0 (3 glds per wave; 64-B rows, 16 rows/sb)
    #pragma unroll
    for (int i = 0; i < 3; ++i) {
        int lin = w * 3 + i, mt = lin >> 2, s = lin & 3;
        glds16(&WT[((size_t)(mt * 16 + h) * 64 + s * 16 + (lane >> 2)) * E_ + (lane & 3) * 8],
               &Wt3[0][mt * 2080 + s * 520]);
    }
    __syncthreads();

    short* xw = &Xs[w * 4608];
    const float* xrowb = &x[(size_t)(m0 + w * 64 + lane) * E_];
    int p = 0;
    for (int k0 = 0; k0 < E_; k0 += 32) {
        if (k0 + 32 < E_) {                 // prefetch next weights -> buf p^1
            #pragma unroll
            for (int i = 0; i < 3; ++i) {
                int lin = w * 3 + i, mt = lin >> 2, s = lin & 3;
                glds16(&WT[((size_t)(mt * 16 + h) * 64 + s * 16 + (lane >> 2)) * E_ + k0 + 32 + (lane & 3) * 8],
                       &Wt3[p ^ 1][mt * 2080 + s * 520]);
            }
        }
        // stage x (wave-private: row = lane, 32 cols)
        float4 xv[8];
        #pragma unroll
        for (int j = 0; j < 8; ++j) xv[j] = *(const float4*)&xrowb[k0 + j * 4];
        #pragma unroll
        for (int j = 0; j < 4; ++j) {
            bf16x8 pk;
            pk[0] = f2bs(xv[2 * j].x);     pk[1] = f2bs(xv[2 * j].y);
            pk[2] = f2bs(xv[2 * j].z);     pk[3] = f2bs(xv[2 * j].w);
            pk[4] = f2bs(xv[2 * j + 1].x); pk[5] = f2bs(xv[2 * j + 1].y);
            pk[6] = f2bs(xv[2 * j + 1].z); pk[7] = f2bs(xv[2 * j + 1].w);
            *(bf16x8*)&xw[lane * 72 + j * 8] = pk;
        }
        asm volatile("s_waitcnt lgkmcnt(0)" ::: "memory");
        // fragments + MFMA (48 per wave)
        bf16x8 a[4];
        #pragma unroll
        for (int mi = 0; mi < 4; ++mi)
            a[mi] = *(const bf16x8*)&xw[(mi * 16 + l15) * 72 + qd * 8];
        #pragma unroll
        for (int mt = 0; mt < 3; ++mt)
            #pragma unroll
            for (int c = 0; c < 4; ++c) {
                bf16x8 bb = *(const bf16x8*)&Wt3[p][mt * 2080 + c * 520 + l15 * 32 + qd * 8];
                #pragma unroll
                for (int mi = 0; mi < 4; ++mi)
                    acc[mt][mi][c] = mfma16(a[mi], bb, acc[mt][mi][c]);
            }
        __syncthreads();
        p ^= 1;
    }

    const int bb = m0 >> 11;
    const int s0 = m0 & (S_ - 1);
    float bqv[4], bkv[4], bvv[4];
    #pragma unroll
    for (int c = 0; c < 4; ++c) {
        int d = c * 16 + l15;
        bqv[c] = bq[h * D_ + d];
        bkv[c] = bk[h * D_ + d];
        bvv[c] = bv[h * D_ + d];
    }
    #pragma unroll
    for (int mi = 0; mi < 4; ++mi)
        #pragma unroll
        for (int c = 0; c < 4; ++c)
            #pragma unroll
            for (int r = 0; r < 4; ++r) {
                int s = s0 + w * 64 + mi * 16 + qd * 4 + r;
                size_t base = (((size_t)bb * H_ + h) * S_ + s) * D_ + c * 16 + l15;
                Qw[base] = f2bs((acc[0][mi][c][r] + bqv[c]) * QSCALE);
                Kw[base] = f2bs(acc[1][mi][c][r] + bkv[c]);
            }
    // V: retile via wave-private LDS (stride 66), store [B,H,D,S]
    short* ep = xw;
    #pragma unroll
    for (int mi = 0; mi < 4; ++mi)
        #pragma unroll
        for (int c = 0; c < 4; ++c)
            #pragma unroll
            for (int r = 0; r < 4; ++r)
                ep[(mi * 16 + qd * 4 + r) * 66 + c * 16 + l15] =
                    f2bs(acc[2][mi][c][r] + bvv[c]);
    asm volatile("s_waitcnt lgkmcnt(0)" ::: "memory");
    const int sr = lane & 31, dh = lane >> 5;
    const size_t vbase = ((size_t)bb * H_ + h) * (size_t)D_ * S_;
    #pragma unroll
    for (int it = 0; it < 64; ++it) {
        int half = it >> 5;
        int dd = (it & 31) * 2 + dh;
        int sr2 = half * 32 + sr;
        VTw[vbase + (size_t)dd * S_ + s0 + w * 64 + sr2] = ep[sr2 * 66 + dd];
    }
}

// ---------------------------------------------------------------------------
// Flash attention. Block (jj,bh) does q-tiles (15-jj),(jj): 34 k-iters total.
// K/V: dbuf glds; Q: direct global->reg frags; fixed-max softmax (exp2).
// ---------------------------------------------------------------------------
__global__ __launch_bounds__(256, 3) void attn(
    const short* __restrict__ Qw, const short* __restrict__ Kw,
    const short* __restrict__ VTw, short* __restrict__ Ow)
{
    const int jj = blockIdx.x;                    // 0..7
    const int bh = blockIdx.y;
    const int b = bh >> 4, h = bh & 15;
    const size_t kbase = ((size_t)b * H_ + h) * (size_t)S_ * D_;
    const size_t vbase = ((size_t)b * H_ + h) * (size_t)D_ * S_;

    __shared__ short Ps[128 * 72];                // P round-trip (wave-private rows)
    __shared__ short Ks[2][8 * 520];              // 64x64 bf16 tile, superblocked
    __shared__ short Vt[2][8 * 520];

    const int tid = threadIdx.x;
    const int lane = tid & 63, w = tid >> 6;
    const int l15 = lane & 15, qd = lane >> 4;
    const int gr = lane >> 3, gc = (lane & 7) * 8;  // glds src row/col-chunk

    #pragma unroll
    for (int phase = 0; phase < 2; ++phase) {
        const int qt = phase ? jj : (15 - jj);

        // Q fragments direct from global (A-layout)
        bf16x8 qf[2][2];
        #pragma unroll
        for (int mi = 0; mi < 2; ++mi)
            #pragma unroll
            for (int t = 0; t < 2; ++t)
                qf[mi][t] = *(const bf16x8*)&Qw[kbase +
                    (size_t)(qt * 128 + w * 32 + mi * 16 + l15) * D_ + t * 32 + qd * 8];

        f32x4 zero = {0.f, 0.f, 0.f, 0.f};
        f32x4 oacc[2][4];
        float lrow[2][4];
        #pragma unroll
        for (int mi = 0; mi < 2; ++mi) {
            #pragma unroll
            for (int c = 0; c < 4; ++c) oacc[mi][c] = zero;
            #pragma unroll
            for (int r = 0; r < 4; ++r) lrow[mi][r] = 0.f;
        }

        const int nkt = (qt + 1) * 2;
        // prologue: tile 0 -> buf 0 (2 K-sbs + 2 V-sbs per wave)
        #pragma unroll
        for (int i = 0; i < 2; ++i) {
            int sb = w * 2 + i;
            glds16(&Kw[kbase + (size_t)(sb * 8 + gr) * D_ + gc], &Ks[0][sb * 520]);
            glds16(&VTw[vbase + (size_t)(sb * 8 + gr) * S_ + gc], &Vt[0][sb * 520]);
        }
        __syncthreads();

        int p = 0;
        for (int kt = 0; kt < nkt; ++kt) {
            if (kt + 1 < nkt) {                   // prefetch next tile -> buf p^1
                #pragma unroll
                for (int i = 0; i < 2; ++i) {
                    int sb = w * 2 + i;
                    glds16(&Kw[kbase + (size_t)((kt + 1) * 64 + sb * 8 + gr) * D_ + gc],
                           &Ks[p ^ 1][sb * 520]);
                    glds16(&VTw[vbase + (size_t)(sb * 8 + gr) * S_ + (kt + 1) * 64 + gc],
                           &Vt[p ^ 1][sb * 520]);
                }
            }
            // S = Q K^T
            f32x4 sc[2][4];
            #pragma unroll
            for (int mi = 0; mi < 2; ++mi)
                #pragma unroll
                for (int c = 0; c < 4; ++c) sc[mi][c] = zero;
            #pragma unroll
            for (int t = 0; t < 2; ++t)
                #pragma unroll
                for (int c = 0; c < 4; ++c) {
                    bf16x8 bk = *(const bf16x8*)&Ks[p][sbi(c * 16 + l15, t * 32 + qd * 8)];
                    sc[0][c] = mfma16(qf[0][t], bk, sc[0][c]);
                    sc[1][c] = mfma16(qf[1][t], bk, sc[1][c]);
                }
            // mask + exp2 + partial row sums + P to wave-private LDS
            #pragma unroll
            for (int mi = 0; mi < 2; ++mi) {
                const int fr = qt * 128 + w * 32 + mi * 16;
                if (kt * 64 + 63 > fr) {          // wave-uniform branch
                    #pragma unroll
                    for (int c = 0; c < 4; ++c) {
                        int col = kt * 64 + c * 16 + l15;
                        #pragma unroll
                        for (int r = 0; r < 4; ++r)
                            if (col > fr + qd * 4 + r) sc[mi][c][r] = -1e30f;
                    }
                }
                #pragma unroll
                for (int c = 0; c < 4; ++c)
                    #pragma unroll
                    for (int r = 0; r < 4; ++r) {
                        float pv = __builtin_amdgcn_exp2f(sc[mi][c][r]);
                        lrow[mi][r] += pv;
                        Ps[(w * 32 + mi * 16 + qd * 4 + r) * 72 + c * 16 + l15] = f2bs(pv);
                    }
            }
            asm volatile("s_waitcnt lgkmcnt(0)" ::: "memory");
            // O += P V
            #pragma unroll
            for (int t = 0; t < 2; ++t) {
                bf16x8 ap0 = *(const bf16x8*)&Ps[(w * 32 + l15) * 72 + t * 32 + qd * 8];
                bf16x8 ap1 = *(const bf16x8*)&Ps[(w * 32 + 16 + l15) * 72 + t * 32 + qd * 8];
                #pragma unroll
                for (int c = 0; c < 4; ++c) {
                    bf16x8 bv = *(const bf16x8*)&Vt[p][sbi(c * 16 + l15, t * 32 + qd * 8)];
                    oacc[0][c] = mfma16(ap0, bv, oacc[0][c]);
                    oacc[1][c] = mfma16(ap1, bv, oacc[1][c]);
                }
            }
            __syncthreads();
            p ^= 1;
        }

        // epilogue: reduce l across quads, normalize, write O
        #pragma unroll
        for (int mi = 0; mi < 2; ++mi) {
            float inv[4];
            #pragma unroll
            for (int r = 0; r < 4; ++r) {
                float l = lrow[mi][r];
                l += __shfl_xor(l, 1);
                l += __shfl_xor(l, 2);
                l += __shfl_xor(l, 4);
                l += __shfl_xor(l, 8);
                inv[r] = 1.f / l;
            }
            #pragma unroll
            for (int c = 0; c < 4; ++c)
                #pragma unroll
                for (int r = 0; r < 4; ++r) {
                    int s = qt * 128 + w * 32 + mi * 16 + qd * 4 + r;
                    Ow[((size_t)b * S_ + s) * (H_ * D_) + h * D_ + c * 16 + l15] =
                        f2bs(oacc[mi][c][r] * inv[r]);
                }
        }
    }
}

// ---------------------------------------------------------------------------
// Output projection: 128x128 block, wave quadrants 64x64, dbuf glds A+B.
// ---------------------------------------------------------------------------
__global__ __launch_bounds__(256, 2) void out_proj(
    const short* __restrict__ Oin, const short* __restrict__ WpT,
    const float* __restrict__ bp, float* __restrict__ out)
{
    const int m0 = blockIdx.x * 128;
    const int n0 = blockIdx.y * 128;
    __shared__ short As[2][16 * 520];     // 128 rows x 64 k, superblocked
    __shared__ short Bs[2][16 * 520];

    const int tid = threadIdx.x;
    const int lane = tid & 63, w = tid >> 6;
    const int l15 = lane & 15, qd = lane >> 4;
    const int gr = lane >> 3, gc = (lane & 7) * 8;
    const int mh = (w & 1) * 64, nh = (w >> 1) * 64;

    f32x4 zero = {0.f, 0.f, 0.f, 0.f};
    f32x4 acc[4][4];
    #pragma unroll
    for (int mi = 0; mi < 4; ++mi)
        #pragma unroll
        for (int c = 0; c < 4; ++c) acc[mi][c] = zero;

    // prologue k0=0 -> buf0: waves 0,1 -> A sbs 0..15; waves 2,3 -> B sbs 0..15
    #pragma unroll
    for (int i = 0; i < 8; ++i) {
        int lin = w * 8 + i;
        if (lin < 16)
            glds16(&Oin[(size_t)(m0 + lin * 8 + gr) * E_ + gc], &As[0][lin * 520]);
        else
            glds16(&WpT[(size_t)(n0 + (lin - 16) * 8 + gr) * E_ + gc], &Bs[0][(lin - 16) * 520]);
    }
    __syncthreads();

    int p = 0;
    for (int k0 = 0; k0 < E_; k0 += 64) {
        if (k0 + 64 < E_) {
            #pragma unroll
            for (int i = 0; i < 8; ++i) {
                int lin = w * 8 + i;
                if (lin < 16)
                    glds16(&Oin[(size_t)(m0 + lin * 8 + gr) * E_ + k0 + 64 + gc],
                           &As[p ^ 1][lin * 520]);
                else
                    glds16(&WpT[(size_t)(n0 + (lin - 16) * 8 + gr) * E_ + k0 + 64 + gc],
                           &Bs[p ^ 1][(lin - 16) * 520]);
            }
        }
        #pragma unroll
        for (int t = 0; t < 2; ++t) {
            bf16x8 a[4];
            #pragma unroll
            for (int mi = 0; mi < 4; ++mi)
                a[mi] = *(const bf16x8*)&As[p][sbi(mh + mi * 16 + l15, t * 32 + qd * 8)];
            #pragma unroll
            for (int c = 0; c < 4; ++c) {
                bf16x8 bb = *(const bf16x8*)&Bs[p][sbi(nh + c * 16 + l15, t * 32 + qd * 8)];
                #pragma unroll
                for (int mi = 0; mi < 4; ++mi)
                    acc[mi][c] = mfma16(a[mi], bb, acc[mi][c]);
            }
        }
        __syncthreads();
        p ^= 1;
    }
    #pragma unroll
    for (int c = 0; c < 4; ++c) {
        float bpv = bp[n0 + nh + c * 16 + l15];
        #pragma unroll
        for (int mi = 0; mi < 4; ++mi)
            #pragma unroll
            for (int r = 0; r < 4; ++r) {
                int m = m0 + mh + mi * 16 + qd * 4 + r;
                out[(size_t)m * E_ + n0 + nh + c * 16 + l15] = acc[mi][c][r] + bpv;
            }
    }
}

// ---------------------------------------------------------------------------
extern "C" void kernel_launch(void* const* d_in, const int* in_sizes, int n_in,
                              void* d_out, int out_size, void* d_ws, size_t ws_size,
                              hipStream_t stream)
{
    const float* x  = (const float*)d_in[0];
    const float* Wq = (const float*)d_in[1];
    const float* bq = (const float*)d_in[2];
    const float* Wk = (const float*)d_in[3];
    const float* bk = (const float*)d_in[4];
    const float* Wv = (const float*)d_in[5];
    const float* bv = (const float*)d_in[6];
    const float* Wp = (const float*)d_in[7];
    const float* bp = (const float*)d_in[8];
    float* out = (float*)d_out;

    const size_t nQKV = (size_t)B_ * H_ * S_ * D_;   // 8,388,608 bf16 elements
    short* Qw   = (short*)d_ws;          // [B,H,S,D]; later reused for WpT
    short* Kw   = Qw + nQKV;             // [B,H,S,D]
    short* VTw  = Kw + nQKV;             // [B,H,D,S]
    short* buf3 = VTw + nQKV;            // WT[48][64][1024] first, then Ow[B,S,HD]
    short* WT   = buf3;
    short* Ow   = buf3;
    short* WpT  = Qw;                    // Qw dead after attn

    conv_wqkv<<<dim3(768), 256, 0, stream>>>(Wq, Wk, Wv, WT);
    qkv_fused<<<dim3(32, 16), 256, 0, stream>>>(x, WT, bq, bk, bv, Qw, Kw, VTw);
    attn<<<dim3(8, 64), 256, 0, stream>>>(Qw, Kw, VTw, Ow);
    conv_wp<<<dim3(256), 256, 0, stream>>>(Wp, WpT);
    out_proj<<<dim3(64, 8), 256, 0, stream>>>(Ow, WpT, bp, out);
}

// Round 5
// 252.321 us; speedup vs baseline: 1.1111x; 1.1111x over previous
//
#include <hip/hip_runtime.h>
#include <hip/hip_bf16.h>

#define B_ 4
#define S_ 2048
#define E_ 1024
#define H_ 16
#define D_ 64
#define QSCALE 0.18033688011112042f  // (1/8) * log2(e) : softmax in exp2 domain

typedef __attribute__((ext_vector_type(8))) short bf16x8;   // 8 bf16 (4 VGPRs)
typedef __attribute__((ext_vector_type(4))) float f32x4;    // 16x16 C/D frag
typedef __attribute__((ext_vector_type(16))) float f32x16;  // 32x32 C/D frag

__device__ __forceinline__ f32x4 mfma16(bf16x8 a, bf16x8 b, f32x4 c) {
    return __builtin_amdgcn_mfma_f32_16x16x32_bf16(a, b, c, 0, 0, 0);
}
__device__ __forceinline__ f32x16 mfma32(bf16x8 a, bf16x8 b, f32x16 c) {
    return __builtin_amdgcn_mfma_f32_32x32x16_bf16(a, b, c, 0, 0, 0);
}
__device__ __forceinline__ short f2bs(float f) {
    __hip_bfloat16 h = __float2bfloat16(f);
    return *reinterpret_cast<short*>(&h);
}

// slab strides (shorts). Slab = one 8-wide k-chunk of all rows. Stride chosen
// so slab-to-slab offset == 4 words mod 32 banks -> staging writes conflict-free.
#define XSLAB 1032   // 128 rows * 8 + 8 pad
#define WSLAB 1544   // 192 rows * 8 + 8 pad

// ---------------------------------------------------------------------------
// Transpose-convert Wq/Wk/Wv (per head [1024][64] fp32) -> WT[48][64][1024] bf16
// ---------------------------------------------------------------------------
__global__ __launch_bounds__(256) void conv_wqkv(
    const float* __restrict__ Wq, const float* __restrict__ Wk,
    const float* __restrict__ Wv, short* __restrict__ WT)
{
    const int mat = blockIdx.x >> 4;
    const int kt  = blockIdx.x & 15;
    const int which = mat >> 4, h = mat & 15;
    const float* src = (which == 0 ? Wq : which == 1 ? Wk : Wv) + (size_t)h * E_ * D_;
    __shared__ float T[64][65];
    const int tid = threadIdx.x;
    const int k0 = kt * 64;
    #pragma unroll
    for (int it = 0; it < 4; ++it) {
        int lin = tid + it * 256;
        int kr = lin >> 4, dc = (lin & 15) * 4;
        const float4 v = *(const float4*)&src[(size_t)(k0 + kr) * D_ + dc];
        T[kr][dc] = v.x; T[kr][dc + 1] = v.y; T[kr][dc + 2] = v.z; T[kr][dc + 3] = v.w;
    }
    __syncthreads();
    #pragma unroll
    for (int it = 0; it < 4; ++it) {
        int lin = tid + it * 256;
        int dr = lin >> 4, kc = (lin & 15) * 4;
        ushort4 o;
        o.x = (unsigned short)f2bs(T[kc][dr]);
        o.y = (unsigned short)f2bs(T[kc + 1][dr]);
        o.z = (unsigned short)f2bs(T[kc + 2][dr]);
        o.w = (unsigned short)f2bs(T[kc + 3][dr]);
        *(ushort4*)&WT[((size_t)mat * 64 + dr) * E_ + k0 + kc] = o;
    }
}

// ---------------------------------------------------------------------------
// Transpose-convert Wp [1024][1024] fp32 -> WpT[n][k] bf16
// ---------------------------------------------------------------------------
__global__ __launch_bounds__(256) void conv_wp(
    const float* __restrict__ Wp, short* __restrict__ WpT)
{
    const int ktile = blockIdx.x & 15, ntile = blockIdx.x >> 4;
    const int k0 = ktile * 64, n0 = ntile * 64;
    __shared__ float T[64][65];
    const int tid = threadIdx.x;
    #pragma unroll
    for (int it = 0; it < 4; ++it) {
        int lin = tid + it * 256;
        int kr = lin >> 4, nc = (lin & 15) * 4;
        const float4 v = *(const float4*)&Wp[(size_t)(k0 + kr) * E_ + n0 + nc];
        T[kr][nc] = v.x; T[kr][nc + 1] = v.y; T[kr][nc + 2] = v.z; T[kr][nc + 3] = v.w;
    }
    __syncthreads();
    #pragma unroll
    for (int it = 0; it < 4; ++it) {
        int lin = tid + it * 256;
        int nr = lin >> 4, kc = (lin & 15) * 4;
        ushort4 o;
        o.x = (unsigned short)f2bs(T[kc][nr]);
        o.y = (unsigned short)f2bs(T[kc + 1][nr]);
        o.z = (unsigned short)f2bs(T[kc + 2][nr]);
        o.w = (unsigned short)f2bs(T[kc + 3][nr]);
        *(ushort4*)&WpT[(size_t)(n0 + nr) * E_ + k0 + kc] = o;
    }
}

// ---------------------------------------------------------------------------
// Fused QKV projection, 32x32x16 MFMA. Block 128 rows x 192 cols (3 mats),
// wave = 64 rows x 96 cols (2x3 frag32). BK=64, register-prefetch pipeline,
// chunked-K slab LDS (conflict-free). V stored transposed [B,H,D,S].
// ---------------------------------------------------------------------------
__global__ __launch_bounds__(256, 2) void qkv_fused(
    const float* __restrict__ x, const short* __restrict__ WT,
    const float* __restrict__ bq, const float* __restrict__ bk,
    const float* __restrict__ bv,
    short* __restrict__ Qw, short* __restrict__ Kw, short* __restrict__ VTw)
{
    const int h = blockIdx.y;
    const int m0 = blockIdx.x * 128;
    __shared__ short SM[8 * XSLAB + 8 * WSLAB];   // 41.2 KB
    short* Xs = SM;
    short* Ws = SM + 8 * XSLAB;

    const int tid = threadIdx.x;
    const int lane = tid & 63, w = tid >> 6;
    const int wm = w & 1, wn = w >> 1;            // wave m-half / n-half
    const int l31 = lane & 31, hi = lane >> 5;
    const int cc = tid & 7, r8 = tid >> 3;        // staging coords

    f32x16 acc[2][3];
    #pragma unroll
    for (int mf = 0; mf < 2; ++mf)
        #pragma unroll
        for (int nf = 0; nf < 3; ++nf)
            #pragma unroll
            for (int i = 0; i < 16; ++i) acc[mf][nf][i] = 0.f;

    float4 xr[4][2];
    bf16x8 wr[6];

    // prologue loads (k0 = 0)
    #pragma unroll
    for (int it = 0; it < 4; ++it) {
        const float* p = &x[(size_t)(m0 + it * 32 + r8) * E_ + cc * 8];
        xr[it][0] = *(const float4*)p;
        xr[it][1] = *(const float4*)(p + 4);
    }
    #pragma unroll
    for (int it = 0; it < 6; ++it) {
        int rg = ((it >> 1) * 16 + h) * 64 + (it & 1) * 32 + r8;
        wr[it] = *(const bf16x8*)&WT[(size_t)rg * E_ + cc * 8];
    }

    for (int k0 = 0; k0 < E_; k0 += 64) {
        // commit staged regs -> LDS slabs
        #pragma unroll
        for (int it = 0; it < 4; ++it) {
            bf16x8 pk;
            pk[0] = f2bs(xr[it][0].x); pk[1] = f2bs(xr[it][0].y);
            pk[2] = f2bs(xr[it][0].z); pk[3] = f2bs(xr[it][0].w);
            pk[4] = f2bs(xr[it][1].x); pk[5] = f2bs(xr[it][1].y);
            pk[6] = f2bs(xr[it][1].z); pk[7] = f2bs(xr[it][1].w);
            *(bf16x8*)&Xs[cc * XSLAB + (it * 32 + r8) * 8] = pk;
        }
        #pragma unroll
        for (int it = 0; it < 6; ++it)
            *(bf16x8*)&Ws[cc * WSLAB + (it * 32 + r8) * 8] = wr[it];
        __syncthreads();
        // issue next tile's loads (latency hidden under MFMA)
        if (k0 + 64 < E_) {
            #pragma unroll
            for (int it = 0; it < 4; ++it) {
                const float* p = &x[(size_t)(m0 + it * 32 + r8) * E_ + k0 + 64 + cc * 8];
                xr[it][0] = *(const float4*)p;
                xr[it][1] = *(const float4*)(p + 4);
            }
            #pragma unroll
            for (int it = 0; it < 6; ++it) {
                int rg = ((it >> 1) * 16 + h) * 64 + (it & 1) * 32 + r8;
                wr[it] = *(const bf16x8*)&WT[(size_t)rg * E_ + k0 + 64 + cc * 8];
            }
        }
        // 4 k-steps x 6 mfma32
        #pragma unroll
        for (int ks = 0; ks < 4; ++ks) {
            const int ccr = ks * 2 + hi;
            bf16x8 a[2], b[3];
            #pragma unroll
            for (int mf = 0; mf < 2; ++mf)
                a[mf] = *(const bf16x8*)&Xs[ccr * XSLAB + (wm * 64 + mf * 32 + l31) * 8];
            #pragma unroll
            for (int nf = 0; nf < 3; ++nf)
                b[nf] = *(const bf16x8*)&Ws[ccr * WSLAB + (wn * 96 + nf * 32 + l31) * 8];
            #pragma unroll
            for (int mf = 0; mf < 2; ++mf)
                #pragma unroll
                for (int nf = 0; nf < 3; ++nf)
                    acc[mf][nf] = mfma32(a[mf], b[nf], acc[mf][nf]);
        }
        __syncthreads();
    }

    // epilogue. C/D 32-shape: col=l31, row=(reg&3)+8*(reg>>2)+4*hi
    const int bb = m0 >> 11;
    const int s0 = m0 & (S_ - 1);
    const size_t qkbase = ((size_t)bb * H_ + h) * S_;
    short* Vr = SM;                                // reuse (size 64*136 shorts)
    #pragma unroll
    for (int mf = 0; mf < 2; ++mf)
        #pragma unroll
        for (int nf = 0; nf < 3; ++nf) {
            const int ng = wn * 96 + nf * 32;      // wave-uniform
            const int mat = ng >> 6;
            const int d = (ng & 63) + l31;
            const int sl0 = wm * 64 + mf * 32 + 4 * hi;
            if (mat == 0) {
                const float bb_ = bq[h * D_ + d];
                #pragma unroll
                for (int rg = 0; rg < 16; ++rg) {
                    int s = s0 + sl0 + (rg & 3) + 8 * (rg >> 2);
                    Qw[(qkbase + s) * D_ + d] = f2bs((acc[mf][nf][rg] + bb_) * QSCALE);
                }
            } else if (mat == 1) {
                const float bb_ = bk[h * D_ + d];
                #pragma unroll
                for (int rg = 0; rg < 16; ++rg) {
                    int s = s0 + sl0 + (rg & 3) + 8 * (rg >> 2);
                    Kw[(qkbase + s) * D_ + d] = f2bs(acc[mf][nf][rg] + bb_);
                }
            } else {
                const float bb_ = bv[h * D_ + d];
                #pragma unroll
                for (int rg = 0; rg < 16; ++rg) {
                    int sl = sl0 + (rg & 3) + 8 * (rg >> 2);
                    Vr[d * 136 + sl] = f2bs(acc[mf][nf][rg] + bb_);
                }
            }
        }
    __syncthreads();
    const size_t vbase = ((size_t)bb * H_ + h) * (size_t)D_ * S_;
    const int sc = tid & 15, dr = tid >> 4;
    #pragma unroll
    for (int it = 0; it < 4; ++it) {
        int d = it * 16 + dr;
        *(bf16x8*)&VTw[vbase + (size_t)d * S_ + s0 + sc * 8] =
            *(const bf16x8*)&Vr[d * 136 + sc * 8];
    }
}

// ---------------------------------------------------------------------------
// Flash attention (round-3 proven version). Fixed-max softmax, paired q-tiles,
// double-buffered K/V LDS with register prefetch.
// ---------------------------------------------------------------------------
__global__ __launch_bounds__(256, 2) void attn(
    const short* __restrict__ Qw, const short* __restrict__ Kw,
    const short* __restrict__ VTw, short* __restrict__ Ow)
{
    const int jj = blockIdx.x;                    // 0..7
    const int bh = blockIdx.y;
    const int b = bh >> 4, h = bh & 15;
    const size_t kbase = ((size_t)b * H_ + h) * (size_t)S_ * D_;
    const size_t vbase = ((size_t)b * H_ + h) * (size_t)D_ * S_;

    __shared__ short Qs[128 * 72];
    __shared__ short Ks[2][64 * 72];
    __shared__ short Vt[2][64 * 72];

    const int tid = threadIdx.x;
    const int lane = tid & 63, w = tid >> 6;
    const int l15 = lane & 15, qd = lane >> 4;

    const int r0s = tid >> 3;
    const int c0s = (tid & 7) * 8;
    const int r1s = r0s + 32;

    #pragma unroll
    for (int phase = 0; phase < 2; ++phase) {
        const int qt = phase ? jj : (15 - jj);

        #pragma unroll
        for (int it = 0; it < 4; ++it) {
            int row = w * 32 + it * 8 + (lane >> 3);
            int cb = (lane & 7) * 8;
            *(bf16x8*)&Qs[row * 72 + cb] =
                *(const bf16x8*)&Qw[kbase + (size_t)(qt * 128 + row) * D_ + cb];
        }
        asm volatile("s_waitcnt lgkmcnt(0)" ::: "memory");
        bf16x8 qf[2][2];
        #pragma unroll
        for (int mi = 0; mi < 2; ++mi)
            #pragma unroll
            for (int t = 0; t < 2; ++t)
                qf[mi][t] = *(const bf16x8*)&Qs[(w * 32 + mi * 16 + l15) * 72 + t * 32 + qd * 8];

        f32x4 zero = {0.f, 0.f, 0.f, 0.f};
        f32x4 oacc[2][4];
        float lrow[2][4];
        #pragma unroll
        for (int mi = 0; mi < 2; ++mi) {
            #pragma unroll
            for (int c = 0; c < 4; ++c) oacc[mi][c] = zero;
            #pragma unroll
            for (int r = 0; r < 4; ++r) lrow[mi][r] = 0.f;
        }

        const int nkt = (qt + 1) * 2;
        bf16x8 kr0, kr1, vr0, vr1;
        kr0 = *(const bf16x8*)&Kw[kbase + (size_t)r0s * D_ + c0s];
        kr1 = *(const bf16x8*)&Kw[kbase + (size_t)r1s * D_ + c0s];
        vr0 = *(const bf16x8*)&VTw[vbase + (size_t)r0s * S_ + c0s];
        vr1 = *(const bf16x8*)&VTw[vbase + (size_t)r1s * S_ + c0s];
        *(bf16x8*)&Ks[0][r0s * 72 + c0s] = kr0;
        *(bf16x8*)&Ks[0][r1s * 72 + c0s] = kr1;
        *(bf16x8*)&Vt[0][r0s * 72 + c0s] = vr0;
        *(bf16x8*)&Vt[0][r1s * 72 + c0s] = vr1;
        __syncthreads();

        int p = 0;
        for (int kt = 0; kt < nkt; ++kt) {
            const bool pre = (kt + 1 < nkt);
            if (pre) {
                kr0 = *(const bf16x8*)&Kw[kbase + (size_t)((kt + 1) * 64 + r0s) * D_ + c0s];
                kr1 = *(const bf16x8*)&Kw[kbase + (size_t)((kt + 1) * 64 + r1s) * D_ + c0s];
                vr0 = *(const bf16x8*)&VTw[vbase + (size_t)r0s * S_ + (kt + 1) * 64 + c0s];
                vr1 = *(const bf16x8*)&VTw[vbase + (size_t)r1s * S_ + (kt + 1) * 64 + c0s];
            }
            f32x4 sc[2][4];
            #pragma unroll
            for (int mi = 0; mi < 2; ++mi)
                #pragma unroll
                for (int c = 0; c < 4; ++c) sc[mi][c] = zero;
            #pragma unroll
            for (int t = 0; t < 2; ++t)
                #pragma unroll
                for (int c = 0; c < 4; ++c) {
                    bf16x8 bk = *(const bf16x8*)&Ks[p][(c * 16 + l15) * 72 + t * 32 + qd * 8];
                    sc[0][c] = mfma16(qf[0][t], bk, sc[0][c]);
                    sc[1][c] = mfma16(qf[1][t], bk, sc[1][c]);
                }
            #pragma unroll
            for (int mi = 0; mi < 2; ++mi) {
                const int fr = qt * 128 + w * 32 + mi * 16;
                if (kt * 64 + 63 > fr) {
                    #pragma unroll
                    for (int c = 0; c < 4; ++c) {
                        int col = kt * 64 + c * 16 + l15;
                        #pragma unroll
                        for (int r = 0; r < 4; ++r)
                            if (col > fr + qd * 4 + r) sc[mi][c][r] = -1e30f;
                    }
                }
                #pragma unroll
                for (int c = 0; c < 4; ++c)
                    #pragma unroll
                    for (int r = 0; r < 4; ++r) {
                        float pv = __builtin_amdgcn_exp2f(sc[mi][c][r]);
                        lrow[mi][r] += pv;
                        Qs[(w * 32 + mi * 16 + qd * 4 + r) * 72 + c * 16 + l15] = f2bs(pv);
                    }
            }
            asm volatile("s_waitcnt lgkmcnt(0)" ::: "memory");
            #pragma unroll
            for (int t = 0; t < 2; ++t) {
                bf16x8 ap0 = *(const bf16x8*)&Qs[(w * 32 + l15) * 72 + t * 32 + qd * 8];
                bf16x8 ap1 = *(const bf16x8*)&Qs[(w * 32 + 16 + l15) * 72 + t * 32 + qd * 8];
                #pragma unroll
                for (int c = 0; c < 4; ++c) {
                    bf16x8 bv = *(const bf16x8*)&Vt[p][(c * 16 + l15) * 72 + t * 32 + qd * 8];
                    oacc[0][c] = mfma16(ap0, bv, oacc[0][c]);
                    oacc[1][c] = mfma16(ap1, bv, oacc[1][c]);
                }
            }
            if (pre) {
                *(bf16x8*)&Ks[1 - p][r0s * 72 + c0s] = kr0;
                *(bf16x8*)&Ks[1 - p][r1s * 72 + c0s] = kr1;
                *(bf16x8*)&Vt[1 - p][r0s * 72 + c0s] = vr0;
                *(bf16x8*)&Vt[1 - p][r1s * 72 + c0s] = vr1;
            }
            __syncthreads();
            p ^= 1;
        }

        #pragma unroll
        for (int mi = 0; mi < 2; ++mi) {
            float inv[4];
            #pragma unroll
            for (int r = 0; r < 4; ++r) {
                float l = lrow[mi][r];
                l += __shfl_xor(l, 1);
                l += __shfl_xor(l, 2);
                l += __shfl_xor(l, 4);
                l += __shfl_xor(l, 8);
                inv[r] = 1.f / l;
            }
            #pragma unroll
            for (int c = 0; c < 4; ++c)
                #pragma unroll
                for (int r = 0; r < 4; ++r) {
                    int s = qt * 128 + w * 32 + mi * 16 + qd * 4 + r;
                    Ow[((size_t)b * S_ + s) * (H_ * D_) + h * D_ + c * 16 + l15] =
                        f2bs(oacc[mi][c][r] * inv[r]);
                }
        }
    }
}

// ---------------------------------------------------------------------------
// Output projection, 32x32x16 MFMA. Block 128x128, wave 64x64 (2x2 frag32),
// BK=64, register-prefetch, chunked-K slab LDS.
// ---------------------------------------------------------------------------
__global__ __launch_bounds__(256, 2) void out_proj(
    const short* __restrict__ Oin, const short* __restrict__ WpT,
    const float* __restrict__ bp, float* __restrict__ out)
{
    const int m0 = blockIdx.x * 128;
    const int n0 = blockIdx.y * 128;
    __shared__ short SM2[16 * XSLAB];             // A slabs + B slabs, 33 KB
    short* As = SM2;
    short* Bs = SM2 + 8 * XSLAB;

    const int tid = threadIdx.x;
    const int lane = tid & 63, w = tid >> 6;
    const int wm = w & 1, wn = w >> 1;
    const int l31 = lane & 31, hi = lane >> 5;
    const int cc = tid & 7, r8 = tid >> 3;

    f32x16 acc[2][2];
    #pragma unroll
    for (int mf = 0; mf < 2; ++mf)
        #pragma unroll
        for (int nf = 0; nf < 2; ++nf)
            #pragma unroll
            for (int i = 0; i < 16; ++i) acc[mf][nf][i] = 0.f;

    bf16x8 ar[4], br[4];
    #pragma unroll
    for (int it = 0; it < 4; ++it) {
        ar[it] = *(const bf16x8*)&Oin[(size_t)(m0 + it * 32 + r8) * E_ + cc * 8];
        br[it] = *(const bf16x8*)&WpT[(size_t)(n0 + it * 32 + r8) * E_ + cc * 8];
    }

    for (int k0 = 0; k0 < E_; k0 += 64) {
        #pragma unroll
        for (int it = 0; it < 4; ++it) {
            *(bf16x8*)&As[cc * XSLAB + (it * 32 + r8) * 8] = ar[it];
            *(bf16x8*)&Bs[cc * XSLAB + (it * 32 + r8) * 8] = br[it];
        }
        __syncthreads();
        if (k0 + 64 < E_) {
            #pragma unroll
            for (int it = 0; it < 4; ++it) {
                ar[it] = *(const bf16x8*)&Oin[(size_t)(m0 + it * 32 + r8) * E_ + k0 + 64 + cc * 8];
                br[it] = *(const bf16x8*)&WpT[(size_t)(n0 + it * 32 + r8) * E_ + k0 + 64 + cc * 8];
            }
        }
        #pragma unroll
        for (int ks = 0; ks < 4; ++ks) {
            const int ccr = ks * 2 + hi;
            bf16x8 a[2], b[2];
            #pragma unroll
            for (int mf = 0; mf < 2; ++mf)
                a[mf] = *(const bf16x8*)&As[ccr * XSLAB + (wm * 64 + mf * 32 + l31) * 8];
            #pragma unroll
            for (int nf = 0; nf < 2; ++nf)
                b[nf] = *(const bf16x8*)&Bs[ccr * XSLAB + (wn * 64 + nf * 32 + l31) * 8];
            #pragma unroll
            for (int mf = 0; mf < 2; ++mf)
                #pragma unroll
                for (int nf = 0; nf < 2; ++nf)
                    acc[mf][nf] = mfma32(a[mf], b[nf], acc[mf][nf]);
        }
        __syncthreads();
    }
    #pragma unroll
    for (int mf = 0; mf < 2; ++mf)
        #pragma unroll
        for (int nf = 0; nf < 2; ++nf) {
            const int n = n0 + wn * 64 + nf * 32 + l31;
            const float bpv = bp[n];
            const int sl0 = wm * 64 + mf * 32 + 4 * hi;
            #pragma unroll
            for (int rg = 0; rg < 16; ++rg) {
                int m = m0 + sl0 + (rg & 3) + 8 * (rg >> 2);
                out[(size_t)m * E_ + n] = acc[mf][nf][rg] + bpv;
            }
        }
}

// ---------------------------------------------------------------------------
extern "C" void kernel_launch(void* const* d_in, const int* in_sizes, int n_in,
                              void* d_out, int out_size, void* d_ws, size_t ws_size,
                              hipStream_t stream)
{
    const float* x  = (const float*)d_in[0];
    const float* Wq = (const float*)d_in[1];
    const float* bq = (const float*)d_in[2];
    const float* Wk = (const float*)d_in[3];
    const float* bk = (const float*)d_in[4];
    const float* Wv = (const float*)d_in[5];
    const float* bv = (const float*)d_in[6];
    const float* Wp = (const float*)d_in[7];
    const float* bp = (const float*)d_in[8];
    float* out = (float*)d_out;

    const size_t nQKV = (size_t)B_ * H_ * S_ * D_;   // 8,388,608 bf16 elements
    short* Qw   = (short*)d_ws;          // [B,H,S,D]; later reused for WpT
    short* Kw   = Qw + nQKV;             // [B,H,S,D]
    short* VTw  = Kw + nQKV;             // [B,H,D,S]
    short* buf3 = VTw + nQKV;            // WT[48][64][1024] first, then Ow[B,S,HD]
    short* WT   = buf3;
    short* Ow   = buf3;
    short* WpT  = Qw;                    // Qw dead after attn

    conv_wqkv<<<dim3(768), 256, 0, stream>>>(Wq, Wk, Wv, WT);
    qkv_fused<<<dim3(64, 16), 256, 0, stream>>>(x, WT, bq, bk, bv, Qw, Kw, VTw);
    attn<<<dim3(8, 64), 256, 0, stream>>>(Qw, Kw, VTw, Ow);
    conv_wp<<<dim3(256), 256, 0, stream>>>(Wp, WpT);
    out_proj<<<dim3(64, 8), 256, 0, stream>>>(Ow, WpT, bp, out);
}